// Round 2
// baseline (1497.146 us; speedup 1.0000x reference)
//
#include <hip/hip_runtime.h>
#include <stdint.h>

#define NL  16
#define NE  16384           // entries per level (power of two)
#define BLK 1024            // threads per block == points per block

constexpr int kRes[NL] = {16,20,25,32,40,50,64,80,101,128,161,203,256,322,406,512};

// ---------------- pre-pass: pack emb (L,2,NE) fp32 -> (L,NE) u32 of 2x bf16 ----------------
__global__ void pack_kernel(const float* __restrict__ emb, uint32_t* __restrict__ tbl) {
    int i = blockIdx.x * blockDim.x + threadIdx.x;     // 0 .. NL*NE-1
    if (i >= NL * NE) return;
    int l = i >> 14;
    int j = i & (NE - 1);
    float e0 = emb[(size_t)l * 2 * NE + j];
    float e1 = emb[(size_t)l * 2 * NE + NE + j];
    uint32_t u0 = __float_as_uint(e0); u0 = (u0 + 0x7fffu + ((u0 >> 16) & 1u)) >> 16;  // RTNE bf16
    uint32_t u1 = __float_as_uint(e1); u1 = (u1 + 0x7fffu + ((u1 >> 16) & 1u)) >> 16;
    tbl[i] = u0 | (u1 << 16);
}

// ---------------- main: per-point all levels, single-buffer LDS, 2 blocks/CU ----------------
__global__ __launch_bounds__(BLK, 8)   // 8 waves/EU = 32 waves/CU = 2 blocks/CU (VGPR <= 64)
void hashenc_kernel(const float* __restrict__ x, const uint32_t* __restrict__ tbl,
                    float* __restrict__ out) {
    __shared__ __align__(16) uint32_t lds[NE];         // 64 KB single buffer -> 2 blocks/CU

    const int tid  = threadIdx.x;
    const size_t b = (size_t)blockIdx.x * BLK + tid;

    const float3 p3 = ((const float3*)x)[b];
    const float pc[3] = {p3.x, p3.y, p3.z};

    // async global->LDS staging: 16 waves x 4 x 1KB chunks, linear lane order
    auto stage = [&](int lvl) {
        const uint32_t* src = tbl + ((size_t)lvl << 14);
        const int wbase = (tid >> 6) * 1024;           // u32 index, per-wave 4KB chunk
        const int lane4 = (tid & 63) * 4;              // 16 B per lane
        #pragma unroll
        for (int p = 0; p < 4; ++p) {
            const int o = wbase + p * 256;
            __builtin_amdgcn_global_load_lds(
                (const __attribute__((address_space(1))) uint32_t*)(src + o + lane4),
                (__attribute__((address_space(3))) uint32_t*)(lds + o),
                16, 0, 0);
        }
    };

    stage(0);

    uint32_t accp[NL];                                 // per-level result, packed bf16x2

    #pragma unroll
    for (int l = 0; l < NL; ++l) {
        __syncthreads();                               // drains vmcnt -> table for level l visible

        const int   res  = kRes[l];
        const float fres = (float)res;
        const bool hashed = (res * res * res > NE);

        // grid_sample align_corners=False unnormalization
        float fr[3]; int c0[3];
        #pragma unroll
        for (int d = 0; d < 3; ++d) {
            float ix = ((pc[d] + 1.0f) * fres - 1.0f) * 0.5f;
            float fl = floorf(ix);
            fr[d] = ix - fl;
            c0[d] = (int)fl;                           // in [-1, res-1]
        }

        // per-dim validity-folded weights + index contributions
        float    w[3][2];
        uint32_t a[3][2];
        #pragma unroll
        for (int d = 0; d < 3; ++d) {
            const int lo = c0[d], hi = c0[d] + 1;
            w[d][0] = (lo >= 0)     ? (1.0f - fr[d]) : 0.0f;   // zero-padding
            w[d][1] = (hi <= res-1) ? fr[d]          : 0.0f;
            const int loc = lo < 0 ? 0 : lo;
            const int hic = hi > res - 1 ? res - 1 : hi;
            if (hashed) {
                constexpr uint32_t P[3] = {1u, 2654435761u, 805459861u};
                a[d][0] = (uint32_t)loc * P[d];
                a[d][1] = (uint32_t)hic * P[d];
            } else {
                const uint32_t stride = (d == 0) ? 1u : ((d == 1) ? (uint32_t)res
                                                                  : (uint32_t)(res * res));
                a[d][0] = (uint32_t)loc * stride;
                a[d][1] = (uint32_t)hic * stride;
            }
        }

        // pairwise-factored xy terms (12 ops instead of 16)
        float    wxy[4];
        uint32_t axy[4];
        #pragma unroll
        for (int c = 0; c < 4; ++c) {
            const int bx = c & 1, by = (c >> 1) & 1;
            wxy[c] = w[0][bx] * w[1][by];
            axy[c] = hashed ? (a[0][bx] ^ a[1][by]) : (a[0][bx] + a[1][by]);
        }

        float f0 = 0.0f, f1 = 0.0f;
        #pragma unroll
        for (int c = 0; c < 8; ++c) {
            const int cxy = c & 3, bz = (c >> 2) & 1;
            const uint32_t idx = hashed
                ? ((axy[cxy] ^ a[2][bz]) & (uint32_t)(NE - 1))
                : (axy[cxy] + a[2][bz]);
            const float wt = wxy[cxy] * w[2][bz];
            const uint32_t v = lds[idx];
            f0 = fmaf(wt, __uint_as_float(v << 16),          f0);  // dim 0 (low bf16)
            f1 = fmaf(wt, __uint_as_float(v & 0xffff0000u),  f1);  // dim 1 (high bf16)
        }

        // pack level result to bf16x2 (round-to-nearest), keep all 16 levels in 16 VGPRs
        {
            uint32_t u0 = (__float_as_uint(f0) + 0x8000u) >> 16;
            uint32_t u1 = (__float_as_uint(f1) + 0x8000u) & 0xffff0000u;
            accp[l] = u0 | u1;
        }

        __syncthreads();                               // all gathers done -> safe to overwrite
        if (l + 1 < NL) stage(l + 1);                  // other block hides this latency
    }

    // one full 128-B line per point: no partial-line RMW
    float4* o = (float4*)(out + b * 32);
    #pragma unroll
    for (int q = 0; q < 8; ++q) {
        const uint32_t v0 = accp[2 * q], v1 = accp[2 * q + 1];
        o[q] = make_float4(__uint_as_float(v0 << 16), __uint_as_float(v0 & 0xffff0000u),
                           __uint_as_float(v1 << 16), __uint_as_float(v1 & 0xffff0000u));
    }
}

extern "C" void kernel_launch(void* const* d_in, const int* in_sizes, int n_in,
                              void* d_out, int out_size, void* d_ws, size_t ws_size,
                              hipStream_t stream) {
    const float* x   = (const float*)d_in[0];   // (B,3) fp32
    const float* emb = (const float*)d_in[1];   // (16,2,16384) fp32
    uint32_t* tbl = (uint32_t*)d_ws;            // (16,16384) packed bf16x2 = 1 MB
    float* out = (float*)d_out;                 // (B,16,2) fp32

    const int npack = NL * NE;
    pack_kernel<<<dim3((npack + 255) / 256), dim3(256), 0, stream>>>(emb, tbl);

    const int nblocks = (1 << 21) / BLK;        // B = 2^21 exactly divisible
    hashenc_kernel<<<dim3(nblocks), dim3(BLK), 0, stream>>>(x, tbl, out);
}

// Round 3
// 652.756 us; speedup vs baseline: 2.2936x; 2.2936x over previous
//
#include <hip/hip_runtime.h>
#include <stdint.h>

#define NL  16
#define NE  16384           // entries per level (power of two)
#define BLK 1024            // threads per block == points per block

constexpr int kRes[NL] = {16,20,25,32,40,50,64,80,101,128,161,203,256,322,406,512};

// ---------------- pre-pass: pack emb (L,2,NE) fp32 -> (L,NE) u32 of 2x bf16 ----------------
__global__ void pack_kernel(const float* __restrict__ emb, uint32_t* __restrict__ tbl) {
    int i = blockIdx.x * blockDim.x + threadIdx.x;     // 0 .. NL*NE-1
    if (i >= NL * NE) return;
    int l = i >> 14;
    int j = i & (NE - 1);
    float e0 = emb[(size_t)l * 2 * NE + j];
    float e1 = emb[(size_t)l * 2 * NE + NE + j];
    uint32_t u0 = __float_as_uint(e0); u0 = (u0 + 0x7fffu + ((u0 >> 16) & 1u)) >> 16;  // RTNE bf16
    uint32_t u1 = __float_as_uint(e1); u1 = (u1 + 0x7fffu + ((u1 >> 16) & 1u)) >> 16;
    tbl[i] = u0 | (u1 << 16);
}

// ---------------- main: per-point all levels, LDS double-buffer, DMA staging ----------------
__global__ __launch_bounds__(BLK, 4)   // 128-VGPR cap: R1 profile (64 VGPR, no spill)
void hashenc_kernel(const float* __restrict__ x, const uint32_t* __restrict__ tbl,
                    float* __restrict__ out) {
    __shared__ __align__(16) uint32_t lds[2][NE];      // 2 x 64 KB double buffer

    const int tid  = threadIdx.x;
    const size_t b = (size_t)blockIdx.x * BLK + tid;

    const float3 p3 = ((const float3*)x)[b];
    const float pc[3] = {p3.x, p3.y, p3.z};

    // async global->LDS staging: wave-uniform LDS base + lane*16 (linear), per-lane global src
    auto stage = [&](int lvl, int buf) {
        const uint32_t* src = tbl + ((size_t)lvl << 14);
        const int wbase = (tid >> 6) * 1024;           // u32 index of this wave's 4KB chunk
        const int lane4 = (tid & 63) * 4;              // 16 B per lane
        #pragma unroll
        for (int p = 0; p < 4; ++p) {
            const int o = wbase + p * 256;
            __builtin_amdgcn_global_load_lds(
                (const __attribute__((address_space(1))) uint32_t*)(src + o + lane4),
                (__attribute__((address_space(3))) uint32_t*)(&lds[buf][o]),
                16, 0, 0);
        }
    };

    stage(0, 0);

    uint32_t accp[NL];                                 // per-level result, packed bf16x2

    #pragma unroll
    for (int l = 0; l < NL; ++l) {
        __syncthreads();   // each wave drained its own vmcnt pre-barrier -> lds[l&1] ready

        if (l + 1 < NL) stage(l + 1, (l + 1) & 1);     // DMA overlaps this level's gathers

        const uint32_t* t = lds[l & 1];
        const int   res  = kRes[l];
        const float fres = (float)res;
        const bool hashed = (res * res * res > NE);

        // grid_sample align_corners=False unnormalization
        float fr[3]; int c0[3];
        #pragma unroll
        for (int d = 0; d < 3; ++d) {
            float ix = ((pc[d] + 1.0f) * fres - 1.0f) * 0.5f;
            float fl = floorf(ix);
            fr[d] = ix - fl;
            c0[d] = (int)fl;                           // in [-1, res-1]
        }

        // per-dim validity-folded weights + index contributions
        float    w[3][2];
        uint32_t a[3][2];
        #pragma unroll
        for (int d = 0; d < 3; ++d) {
            const int lo = c0[d], hi = c0[d] + 1;
            w[d][0] = (lo >= 0)     ? (1.0f - fr[d]) : 0.0f;   // zero-padding
            w[d][1] = (hi <= res-1) ? fr[d]          : 0.0f;
            const int loc = lo < 0 ? 0 : lo;
            const int hic = hi > res - 1 ? res - 1 : hi;
            if (hashed) {
                constexpr uint32_t P[3] = {1u, 2654435761u, 805459861u};
                a[d][0] = (uint32_t)loc * P[d];
                a[d][1] = (uint32_t)hic * P[d];
            } else {
                const uint32_t stride = (d == 0) ? 1u : ((d == 1) ? (uint32_t)res
                                                                  : (uint32_t)(res * res));
                a[d][0] = (uint32_t)loc * stride;
                a[d][1] = (uint32_t)hic * stride;
            }
        }

        // pairwise-factored xy terms (12 ops instead of 16)
        float    wxy[4];
        uint32_t axy[4];
        #pragma unroll
        for (int c = 0; c < 4; ++c) {
            const int bx = c & 1, by = (c >> 1) & 1;
            wxy[c] = w[0][bx] * w[1][by];
            axy[c] = hashed ? (a[0][bx] ^ a[1][by]) : (a[0][bx] + a[1][by]);
        }

        float f0 = 0.0f, f1 = 0.0f;
        #pragma unroll
        for (int c = 0; c < 8; ++c) {
            const int cxy = c & 3, bz = (c >> 2) & 1;
            const uint32_t idx = hashed
                ? ((axy[cxy] ^ a[2][bz]) & (uint32_t)(NE - 1))
                : (axy[cxy] + a[2][bz]);
            const float wt = wxy[cxy] * w[2][bz];
            const uint32_t v = t[idx];
            f0 = fmaf(wt, __uint_as_float(v << 16),          f0);  // dim 0 (low bf16)
            f1 = fmaf(wt, __uint_as_float(v & 0xffff0000u),  f1);  // dim 1 (high bf16)
        }

        // pack level result to bf16x2 (round-to-nearest-up, error <= 0.5 ulp vs fp32)
        {
            uint32_t u0 = (__float_as_uint(f0) + 0x8000u) >> 16;
            uint32_t u1 = (__float_as_uint(f1) + 0x8000u) & 0xffff0000u;
            accp[l] = u0 | u1;
        }
    }

    // one full 128-B line per point: full-line store, no write-allocate RMW
    float4* o = (float4*)(out + b * 32);
    #pragma unroll
    for (int q = 0; q < 8; ++q) {
        const uint32_t v0 = accp[2 * q], v1 = accp[2 * q + 1];
        o[q] = make_float4(__uint_as_float(v0 << 16), __uint_as_float(v0 & 0xffff0000u),
                           __uint_as_float(v1 << 16), __uint_as_float(v1 & 0xffff0000u));
    }
}

extern "C" void kernel_launch(void* const* d_in, const int* in_sizes, int n_in,
                              void* d_out, int out_size, void* d_ws, size_t ws_size,
                              hipStream_t stream) {
    const float* x   = (const float*)d_in[0];   // (B,3) fp32
    const float* emb = (const float*)d_in[1];   // (16,2,16384) fp32
    uint32_t* tbl = (uint32_t*)d_ws;            // (16,16384) packed bf16x2 = 1 MB
    float* out = (float*)d_out;                 // (B,16,2) fp32

    const int npack = NL * NE;
    pack_kernel<<<dim3((npack + 255) / 256), dim3(256), 0, stream>>>(emb, tbl);

    const int nblocks = (1 << 21) / BLK;        // B = 2^21 exactly divisible
    hashenc_kernel<<<dim3(nblocks), dim3(BLK), 0, stream>>>(x, tbl, out);
}